// Round 9
// baseline (377.654 us; speedup 1.0000x reference)
//
#include <hip/hip_runtime.h>

// Conv1dFFTInt8: B=16, CIN=128, COUT=128, L=4096, out_size==1.
// Identity: ifft(sum_l X[l]W[l])[0] = sum_n x[n] * w[(L-n) mod L]  (real inputs)
// => out[b,o] = bias[o] + sum_i sum_m w[o,i,m] * x[b,i,(L-m)&(L-1)]
//
// Ledger: dur_us = conv + ~267us harness const. R8 conv ~106us vs ~48us floor.
// R4/R6/R8 all 105-115us across schedule variants -> schedule micro-structure
// is not the lever. Theory: every weight row is 16KB-aligned and every block
// walks rows with the SAME m-phase (launched together, barrier-relocked), so
// at any instant all ~4k streams read the same intra-row offset -> same HBM
// channel subset -> channel hotspot, ~2.6 TB/s effective. fillBuffer (spread
// absolute addresses) gets 6.6.
// This round: R8 + per-ci chunk-order rotation (q0 = ci & 15). K-sum is
// order-independent; rotation enters ADDRESSES only (rule #20 safe). The 8
// ot-siblings of a ci share q0 -> x L2 reuse preserved; the 16 ci-classes
// spread reads across the whole 16KB row span -> all channels busy.

constexpr int LEN   = 4096;
constexpr int CIN_  = 128;
constexpr int COUT_ = 128;
constexpr int BATCH = 16;

typedef float f32x4 __attribute__((ext_vector_type(4)));

__global__ void init_out_kernel(const float* __restrict__ bias, float* __restrict__ out) {
    int t = blockIdx.x * 256 + threadIdx.x;
    if (t < BATCH * COUT_) out[t] = bias[t & (COUT_ - 1)];
}

// Non-temporal 16B weight load: read-once stream, keep L2 for x.
__device__ __forceinline__ f32x4 ntload4(const float* p) {
    return __builtin_nontemporal_load((const f32x4*)p);
}

// Async 4B global->LDS. LDS dest is wave-uniform base (+lane*4 in HW);
// the index reversal lives in the per-lane GLOBAL address.
__device__ __forceinline__ void gload_lds4(const float* g, float* l) {
    __builtin_amdgcn_global_load_lds(
        (const __attribute__((address_space(1))) unsigned int*)g,
        (__attribute__((address_space(3))) unsigned int*)l, 4, 0, 0);
}

// Wave wv stages batches 4wv..4wv+3 for one 256-float chunk at m0:
// buf[b*256 + u] = x[b, ci, (LEN - m0 - u) & 4095], u in [0,256). 16 gloads.
#define STAGE(BUF, M0)                                                     \
    {                                                                      \
        _Pragma("unroll")                                                  \
        for (int t = 0; t < 4; ++t) {                                      \
            const int n = (LEN - (M0) - (t << 6) - lane) & (LEN - 1);      \
            gload_lds4(xc0 + n, (BUF) + ((4 * wv + 0) << 8) + (t << 6));   \
            gload_lds4(xc1 + n, (BUF) + ((4 * wv + 1) << 8) + (t << 6));   \
            gload_lds4(xc2 + n, (BUF) + ((4 * wv + 2) << 8) + (t << 6));   \
            gload_lds4(xc3 + n, (BUF) + ((4 * wv + 3) << 8) + (t << 6));   \
        }                                                                  \
    }

// 256 FMAs against one chunk: 16 ds_read_b128, weight regs WC[0..3] (static).
#define COMPUTE(BUF, WC)                                                   \
    {                                                                      \
        const float4* xb = (const float4*)(BUF);                           \
        _Pragma("unroll")                                                  \
        for (int b = 0; b < 16; ++b) {                                     \
            const float4 xv = xb[(b << 6) + lane];                         \
            _Pragma("unroll")                                              \
            for (int j = 0; j < 4; ++j) {                                  \
                acc[b][j] += xv.x * WC[j].x;                               \
                acc[b][j] += xv.y * WC[j].y;                               \
                acc[b][j] += xv.z * WC[j].z;                               \
                acc[b][j] += xv.w * WC[j].w;                               \
            }                                                              \
        }                                                                  \
    }

// Block: 256 threads = 4 waves, each wave 4 o-rows (16/block), ONE channel,
// 16 chunks of 256 traversed in rotated order starting at q0 = ci & 15.
// Grid = 8 ot * 128 ci = 1024 = 4 blocks/CU, one pass. bk%8==ci%8: the 8
// ot-siblings sharing a channel land on one XCD (x L2-hits, same q0 phase).
// __launch_bounds__(256,2): empirical hipcc VGPR cap = 256/arg = 128.
__global__ __launch_bounds__(256, 2)
void conv_fft_dot_kernel(const float* __restrict__ x, const float* __restrict__ w,
                         float* __restrict__ out) {
    // 32 KB total: two 16KB x-buffers; epilogue (64 rows * 68) overlays buf0.
    __shared__ float lds[8192];

    const int tid   = threadIdx.x;
    const int lane  = tid & 63;
    const int wv    = __builtin_amdgcn_readfirstlane(tid >> 6);
    const int bk    = blockIdx.x;
    const int ot    = bk >> 7;     // 0..7
    const int ci    = bk & 127;    // input channel
    const int obase = ot * 16 + wv * 4;
    const int q0    = ci & 15;     // per-ci chunk-phase rotation

    // wave-uniform bases (SGPR): per-lane part stays a shared 32-bit offset
    const float* xc0 = x + (((4 * wv + 0) * CIN_ + ci) << 12);
    const float* xc1 = x + (((4 * wv + 1) * CIN_ + ci) << 12);
    const float* xc2 = x + (((4 * wv + 2) * CIN_ + ci) << 12);
    const float* xc3 = x + (((4 * wv + 3) * CIN_ + ci) << 12);
    const float* wr0 = w + (((obase + 0) * CIN_ + ci) << 12);
    const float* wr1 = w + (((obase + 1) * CIN_ + ci) << 12);
    const float* wr2 = w + (((obase + 2) * CIN_ + ci) << 12);
    const float* wr3 = w + (((obase + 3) * CIN_ + ci) << 12);
    const int lo = lane << 2;   // float offset of this lane's float4 in a chunk

    float acc[16][4];
#pragma unroll
    for (int b = 0; b < 16; ++b)
#pragma unroll
        for (int j = 0; j < 4; ++j) acc[b][j] = 0.f;

    f32x4 wcA[4], wcB[4];

    // ---- prologue: stage chunk q0, then its weights (the 4 newest vm ops)
    {
        const int m0 = q0 << 8;
        STAGE(lds, m0)
        __builtin_amdgcn_sched_barrier(0);       // stage strictly before weights
        wcA[0] = ntload4(wr0 + m0 + lo); wcA[1] = ntload4(wr1 + m0 + lo);
        wcA[2] = ntload4(wr2 + m0 + lo); wcA[3] = ntload4(wr3 + m0 + lo);
    }
    asm volatile("s_waitcnt vmcnt(4)" ::: "memory");  // drain stage, keep wcA
    __builtin_amdgcn_s_barrier();
    __builtin_amdgcn_sched_barrier(0);

    // ---- 16 chunks in rotated order, 2-phase unrolled: even->buf0/wcA,
    // odd->buf1/wcB. Chunk index enters addresses only.
#pragma unroll 1
    for (int k = 0; k < 16; k += 2) {
        {   // even phase: compute chunk (q0+k), prefetch (q0+k+1) -> buf1/wcB
            const int m1 = (((q0 + k + 1) & 15)) << 8;
            STAGE(lds + 4096, m1)
            __builtin_amdgcn_sched_barrier(0);   // stage before weight loads
            wcB[0] = ntload4(wr0 + m1 + lo);
            wcB[1] = ntload4(wr1 + m1 + lo);
            wcB[2] = ntload4(wr2 + m1 + lo);
            wcB[3] = ntload4(wr3 + m1 + lo);
            __builtin_amdgcn_sched_barrier(0);   // loads issued before compute
            COMPUTE(lds, wcA)
            asm volatile("s_waitcnt vmcnt(4)" ::: "memory");  // drain stage, keep wcB
            __builtin_amdgcn_s_barrier();
            __builtin_amdgcn_sched_barrier(0);
        }
        {   // odd phase: compute chunk (q0+k+1), prefetch (q0+k+2) -> buf0/wcA
            if (k < 14) {
                const int m2 = (((q0 + k + 2) & 15)) << 8;
                STAGE(lds, m2)
                __builtin_amdgcn_sched_barrier(0);
                wcA[0] = ntload4(wr0 + m2 + lo);
                wcA[1] = ntload4(wr1 + m2 + lo);
                wcA[2] = ntload4(wr2 + m2 + lo);
                wcA[3] = ntload4(wr3 + m2 + lo);
            }
            __builtin_amdgcn_sched_barrier(0);
            COMPUTE(lds + 4096, wcB)
            if (k < 14) {
                asm volatile("s_waitcnt vmcnt(4)" ::: "memory");
                __builtin_amdgcn_s_barrier();
                __builtin_amdgcn_sched_barrier(0);
            }
        }
    }

    // ---- epilogue: cross-lane sum via padded LDS transpose in the dead
    // x-buffer (64 rows * 68 floats = 17KB <= 32KB). 4 fully-static passes
    // (rule #20: every acc index compile-time).
    __syncthreads();
#pragma unroll
    for (int p = 0; p < 4; ++p) {
        if (p) __syncthreads();
#pragma unroll
        for (int bb = 0; bb < 4; ++bb)
#pragma unroll
            for (int j = 0; j < 4; ++j)
                lds[(wv * 16 + bb * 4 + j) * 68 + lane] = acc[p * 4 + bb][j];
        __syncthreads();
        if (tid < 64) {
            const float4* row = (const float4*)(lds + tid * 68);  // 272B: 16B-aligned
            float sum = 0.f;
#pragma unroll
            for (int l = 0; l < 16; ++l) {
                const float4 v = row[l];
                sum += v.x + v.y + v.z + v.w;
            }
            const int o = ot * 16 + (tid >> 4) * 4 + (tid & 3);
            const int b = p * 4 + ((tid >> 2) & 3);
            atomicAdd(out + b * COUT_ + o, sum);
        }
    }
}

extern "C" void kernel_launch(void* const* d_in, const int* in_sizes, int n_in,
                              void* d_out, int out_size, void* d_ws, size_t ws_size,
                              hipStream_t stream) {
    const float* x    = (const float*)d_in[0];   // [16,128,4096]
    const float* wgt  = (const float*)d_in[1];   // [128,128,4096]
    const float* bias = (const float*)d_in[2];   // [128]
    float* out = (float*)d_out;                  // [16,128,1]
    (void)in_sizes; (void)n_in; (void)d_ws; (void)ws_size; (void)out_size;

    init_out_kernel<<<8, 256, 0, stream>>>(bias, out);
    conv_fft_dot_kernel<<<1024, 256, 0, stream>>>(x, wgt, out);
}